// Round 7
// baseline (208.451 us; speedup 1.0000x reference)
//
#include <hip/hip_runtime.h>

// Shapes: tarsent [8,512,512] f32, tar_func [8,512] i32,
//         refsent [8,32,256,512] f32, ref_func [8,32,256] i32.
// Output flat-concat f32 (masks as 0.0/1.0):
//   tar_aug[8,5,512]@0  tar_aug_mask[8,5]@20480  ref_aug[8,32,5,512]@20520
//   ref_aug_mask[8,32,5]@675880  tarpaper[8,512]@677160  tar_mask2[8]@681256
//   refpaper[8,32,512]@681264  ref_mask2[8,32]@812336   total 812592

#define H      512
#define HV     128
#define NL     5
#define BIGF   1e11f
#define CHUNK  64          // sentences per stage-1 block
#define RPB    2           // rows per buffer per wave
#define NBUF   8           // buffers per wave (16 rows/wave * 4 waves = 64)

#define OFF_TAR_AUG       0
#define OFF_TAR_AUG_MASK  20480
#define OFF_REF_AUG       20520
#define OFF_REF_AUG_MASK  675880
#define OFF_TARPAPER      677160
#define OFF_TAR_MASK2     681256
#define OFF_REFPAPER      681264
#define OFF_REF_MASK2     812336

#define NCHUNK_REF 4       // 256 / 64
#define NCHUNK_TAR 8       // 512 / 64
#define NBLK_REF   1024    // 256 segs * 4
#define NBLK1      1088    // + 8 segs * 8
#define WSUM_ELEMS ((size_t)NBLK1 * NL * H)      // 11.1 MB
#define WCNT_OFF_B (WSUM_ELEMS * 4)
#define WS_NEED    (WCNT_OFF_B + (size_t)NBLK1 * NL * 4)

__device__ inline float4 f4add(float4 a, float4 b) {
    a.x += b.x; a.y += b.y; a.z += b.z; a.w += b.w; return a;
}
__device__ inline float4 f4scale(float4 a, float s) {
    a.x *= s; a.y *= s; a.z *= s; a.w *= s; return a;
}
__device__ inline float4 f4fma(float w, float4 v, float4 a) {
    a.x = fmaf(w, v.x, a.x); a.y = fmaf(w, v.y, a.y);
    a.z = fmaf(w, v.z, a.z); a.w = fmaf(w, v.w, a.w); return a;
}
// Direct global->LDS DMA, 16 B per lane; LDS dest = uniform base + lane*16.
__device__ inline void async_copy16(const float* g, float* l) {
    __builtin_amdgcn_global_load_lds(
        (const __attribute__((address_space(1))) void*)g,
        (__attribute__((address_space(3))) void*)l, 16, 0, 0);
}

// ---------------- Stage 1 ---------------------------------------------------
// Wave-private double-buffered LDS pipeline: each wave stages its own rows via
// global_load_lds into a private 2x4KB region, gated only by its own vmcnt.
// NO __syncthreads in the streaming loop -> loads stay in flight continuously.
__global__ __launch_bounds__(256) void emenc_stage1(
    const float* __restrict__ tar_state, const int* __restrict__ tar_func,
    const float* __restrict__ ref_state, const int* __restrict__ ref_func,
    float* __restrict__ wsum, int* __restrict__ wcnt)
{
    __shared__ float sbuf[4 * 2 * RPB * 512];   // 4 waves x 2 regions x 4 KB = 32 KB
    __shared__ int   crow[CHUNK];               // compacted non-pad row indices
    __shared__ int   clab[CHUNK];               // compacted labels
    __shared__ int   scnt5[NL];
    __shared__ int   sm;

    const int b = blockIdx.x;
    const float* state;
    const int*   func;
    int s0;
    if (b < NBLK_REF) {
        const int seg = b >> 2, ch = b & 3;
        state = ref_state + (size_t)seg * 256 * H;
        func  = ref_func  + seg * 256;
        s0    = ch * CHUNK;
    } else {
        const int q = b - NBLK_REF;
        const int seg = q >> 3, ch = q & 7;
        state = tar_state + (size_t)seg * 512 * H;
        func  = tar_func  + seg * 512;
        s0    = ch * CHUNK;
    }

    const int tid  = threadIdx.x;
    const int wv   = tid >> 6;       // wave 0..3
    const int lane = tid & 63;

    // Wave 0: counts + non-pad compaction via ballots.
    if (tid < CHUNK) {
        const int l = func[s0 + tid];
        #pragma unroll
        for (int q = 1; q <= NL; ++q) {
            const unsigned long long mq = __ballot(l == q);
            if (tid == 0) scnt5[q - 1] = (int)__popcll(mq);
        }
        const unsigned long long mask = __ballot(l != 0);
        if (l != 0) {
            const int pos = (int)__popcll(mask & ((1ull << tid) - 1ull));
            crow[pos] = tid;
            clab[pos] = l;
        }
        if (tid == 0) sm = (int)__popcll(mask);
    }
    __syncthreads();

    const int m = sm;                // non-pad rows in this chunk (<= 64)

    float4 acc[NL][2];
    #pragma unroll
    for (int l = 0; l < NL; ++l) {
        acc[l][0] = make_float4(0,0,0,0);
        acc[l][1] = make_float4(0,0,0,0);
    }

    if (m > 0) {
        // Issue 4 DMAs (2 rows x 2 halves) for buffer j into region j&1.
        // Invalid rows clamp to m-1 (redundant load, never accumulated) so the
        // vmcnt arithmetic stays constant.
        auto issue = [&](int j) {
            #pragma unroll
            for (int r = 0; r < RPB; ++r) {
                int idx = j * 8 + wv * RPB + r;      // wave-uniform
                if (idx >= m) idx = m - 1;
                const int row = crow[idx];
                const float* gb = state + (size_t)(s0 + row) * H;
                float* lb = sbuf + ((wv * 2 + (j & 1)) * RPB + r) * 512;
                async_copy16(gb + lane * 4, lb);
                async_copy16(gb + 256 + lane * 4, lb + 256);
            }
        };

        issue(0);
        issue(1);

        #pragma unroll
        for (int j = 0; j < NBUF; ++j) {
            if (j < NBUF - 1) asm volatile("s_waitcnt vmcnt(4)" ::: "memory");
            else              asm volatile("s_waitcnt vmcnt(0)" ::: "memory");

            const float* lb = sbuf + (wv * 2 + (j & 1)) * RPB * 512;
            #pragma unroll
            for (int r = 0; r < RPB; ++r) {
                const int idx = j * 8 + wv * RPB + r;   // wave-uniform
                if (idx < m) {
                    const int l = clab[idx];
                    const float w1 = (l == 1) ? 1.0f : 0.0f;
                    const float w2 = (l == 2) ? 1.0f : 0.0f;
                    const float w3 = (l == 3) ? 1.0f : 0.0f;
                    const float w4 = (l == 4) ? 1.0f : 0.0f;
                    const float w5 = (l == 5) ? 1.0f : 0.0f;
                    const float4 v0 = *(const float4*)(lb + r * 512 + lane * 4);
                    const float4 v1 = *(const float4*)(lb + r * 512 + 256 + lane * 4);
                    acc[0][0] = f4fma(w1, v0, acc[0][0]);
                    acc[0][1] = f4fma(w1, v1, acc[0][1]);
                    acc[1][0] = f4fma(w2, v0, acc[1][0]);
                    acc[1][1] = f4fma(w2, v1, acc[1][1]);
                    acc[2][0] = f4fma(w3, v0, acc[2][0]);
                    acc[2][1] = f4fma(w3, v1, acc[2][1]);
                    acc[3][0] = f4fma(w4, v0, acc[3][0]);
                    acc[3][1] = f4fma(w4, v1, acc[3][1]);
                    acc[4][0] = f4fma(w5, v0, acc[4][0]);
                    acc[4][1] = f4fma(w5, v1, acc[4][1]);
                }
            }
            if (j + 2 < NBUF) {
                // compiler barrier: keep the ds_reads above before re-issue
                asm volatile("" ::: "memory");
                issue(j + 2);
            }
        }
    }

    // ---- cross-wave combine (reuses sbuf; only now do we barrier) ----
    __syncthreads();
    float* flat = sbuf;
    // lane holds cols lane (half 0) and 64+lane (half 1) of each 512-row.
    if (wv >= 2) {
        float* dst = flat + (wv - 2) * (NL * 512);
        #pragma unroll
        for (int l = 0; l < NL; ++l) {
            *(float4*)(dst + l * 512 + lane * 4)       = acc[l][0];
            *(float4*)(dst + l * 512 + 256 + lane * 4) = acc[l][1];
        }
    }
    __syncthreads();
    if (wv < 2) {
        const float* src = flat + wv * (NL * 512);
        #pragma unroll
        for (int l = 0; l < NL; ++l) {
            acc[l][0] = f4add(acc[l][0], *(const float4*)(src + l * 512 + lane * 4));
            acc[l][1] = f4add(acc[l][1], *(const float4*)(src + l * 512 + 256 + lane * 4));
        }
    }
    __syncthreads();
    if (wv == 1) {
        float* dst = flat;
        #pragma unroll
        for (int l = 0; l < NL; ++l) {
            *(float4*)(dst + l * 512 + lane * 4)       = acc[l][0];
            *(float4*)(dst + l * 512 + 256 + lane * 4) = acc[l][1];
        }
    }
    __syncthreads();
    if (wv == 0) {
        const float* src = flat;
        float* wb = wsum + (size_t)b * NL * H;
        #pragma unroll
        for (int l = 0; l < NL; ++l) {
            float4 s0v = f4add(acc[l][0], *(const float4*)(src + l * 512 + lane * 4));
            float4 s1v = f4add(acc[l][1], *(const float4*)(src + l * 512 + 256 + lane * 4));
            *(float4*)(wb + l * H + lane * 4)       = s0v;
            *(float4*)(wb + l * H + 256 + lane * 4) = s1v;
        }
    }
    if (tid < NL) wcnt[b * NL + tid] = scnt5[tid];
}

// ---------------- Stage 2: one block per (segment, role) ------------------
__global__ __launch_bounds__(128) void emenc_stage2(
    const float* __restrict__ wsum, const int* __restrict__ wcnt,
    float* __restrict__ out)
{
    const int bb   = blockIdx.x;
    const int seg  = bb / 6;
    const int role = bb - seg * 6;

    int nch, wb0;
    float *aug, *augmask, *paper, *mask2;
    if (seg < 256) {
        nch = NCHUNK_REF; wb0 = seg * NCHUNK_REF;
        aug     = out + OFF_REF_AUG      + (size_t)seg * NL * H;
        augmask = out + OFF_REF_AUG_MASK + seg * NL;
        paper   = out + OFF_REFPAPER     + (size_t)seg * H;
        mask2   = out + OFF_REF_MASK2    + seg;
    } else {
        const int q = seg - 256;
        nch = NCHUNK_TAR; wb0 = NBLK_REF + q * NCHUNK_TAR;
        aug     = out + OFF_TAR_AUG      + (size_t)q * NL * H;
        augmask = out + OFF_TAR_AUG_MASK + q * NL;
        paper   = out + OFF_TARPAPER     + (size_t)q * H;
        mask2   = out + OFF_TAR_MASK2    + q;
    }

    const int col = threadIdx.x;

    if (role < NL) {
        int c = 0;
        for (int ch = 0; ch < nch; ch++) c += wcnt[(wb0 + ch) * NL + role];
        float4 s = {0,0,0,0};
        for (int ch = 0; ch < nch; ch++)
            s = f4add(s, ((const float4*)(wsum + (size_t)(wb0 + ch) * NL * H
                                          + (size_t)role * H))[col]);
        const float inv = 1.0f / (c > 0 ? (float)c : BIGF);
        ((float4*)(aug + (size_t)role * H))[col] = f4scale(s, inv);
        if (col == 0) augmask[role] = c > 0 ? 1.0f : 0.0f;
    } else {
        int ct = 0;
        for (int ch = 0; ch < nch; ch++) {
            #pragma unroll
            for (int l = 0; l < NL; l++) ct += wcnt[(wb0 + ch) * NL + l];
        }
        float4 t = {0,0,0,0};
        for (int ch = 0; ch < nch; ch++) {
            const float4* wb = (const float4*)(wsum + (size_t)(wb0 + ch) * NL * H);
            #pragma unroll
            for (int l = 0; l < NL; l++) t = f4add(t, wb[l * HV + col]);
        }
        ((float4*)paper)[col] = f4scale(t, 1.0f / (ct > 0 ? (float)ct : BIGF));
        if (col == 0) mask2[0] = ct > 0 ? 1.0f : 0.0f;
    }
}

// ---------------- Fallback (single-stage) if ws too small ------------------
__global__ __launch_bounds__(256) void emenc_single(
    const float* __restrict__ tar_state, const int* __restrict__ tar_func,
    const float* __restrict__ ref_state, const int* __restrict__ ref_func,
    float* __restrict__ out)
{
    __shared__ int    sfunc[512];
    __shared__ float4 spart[HV * NL];
    __shared__ int    scnt[NL];

    const int b = blockIdx.x;
    const float* state;
    const int*   func;
    int S;
    float *aug, *augmask, *paper, *mask2;

    if (b < 256) {
        state   = ref_state + (size_t)b * 256 * H;
        func    = ref_func  + b * 256;
        S       = 256;
        aug     = out + OFF_REF_AUG      + (size_t)b * NL * H;
        augmask = out + OFF_REF_AUG_MASK + b * NL;
        paper   = out + OFF_REFPAPER     + (size_t)b * H;
        mask2   = out + OFF_REF_MASK2    + b;
    } else {
        const int q = b - 256;
        state   = tar_state + (size_t)q * 512 * H;
        func    = tar_func  + q * 512;
        S       = 512;
        aug     = out + OFF_TAR_AUG      + (size_t)q * NL * H;
        augmask = out + OFF_TAR_AUG_MASK + q * NL;
        paper   = out + OFF_TARPAPER     + (size_t)q * H;
        mask2   = out + OFF_TAR_MASK2    + q;
    }

    const int tid = threadIdx.x;
    for (int i = tid; i < S; i += 256) sfunc[i] = func[i];
    __syncthreads();

    const int col   = tid & (HV - 1);
    const int phase = tid >> 7;

    float4 a1 = {0,0,0,0}, a2 = {0,0,0,0}, a3 = {0,0,0,0},
           a4 = {0,0,0,0}, a5 = {0,0,0,0};

    for (int s = phase; s < S; s += 2) {
        float4 v = ((const float4*)(state + (size_t)s * H))[col];
        const int l = sfunc[s];
        a1 = f4fma((l == 1) ? 1.0f : 0.0f, v, a1);
        a2 = f4fma((l == 2) ? 1.0f : 0.0f, v, a2);
        a3 = f4fma((l == 3) ? 1.0f : 0.0f, v, a3);
        a4 = f4fma((l == 4) ? 1.0f : 0.0f, v, a4);
        a5 = f4fma((l == 5) ? 1.0f : 0.0f, v, a5);
    }

    if (phase == 1) {
        spart[col * NL + 0] = a1;
        spart[col * NL + 1] = a2;
        spart[col * NL + 2] = a3;
        spart[col * NL + 3] = a4;
        spart[col * NL + 4] = a5;
    }
    if (tid < NL) {
        int c = 0;
        for (int i = 0; i < S; ++i) c += (sfunc[i] == tid + 1) ? 1 : 0;
        scnt[tid] = c;
    }
    __syncthreads();

    if (phase == 0) {
        a1 = f4add(a1, spart[col * NL + 0]);
        a2 = f4add(a2, spart[col * NL + 1]);
        a3 = f4add(a3, spart[col * NL + 2]);
        a4 = f4add(a4, spart[col * NL + 3]);
        a5 = f4add(a5, spart[col * NL + 4]);

        const int c1 = scnt[0], c2 = scnt[1], c3 = scnt[2],
                  c4 = scnt[3], c5 = scnt[4];
        float4 t  = f4add(f4add(f4add(a1, a2), f4add(a3, a4)), a5);
        const int ct = c1 + c2 + c3 + c4 + c5;

        ((float4*)(aug + 0 * H))[col] = f4scale(a1, 1.0f / (c1 > 0 ? (float)c1 : BIGF));
        ((float4*)(aug + 1 * H))[col] = f4scale(a2, 1.0f / (c2 > 0 ? (float)c2 : BIGF));
        ((float4*)(aug + 2 * H))[col] = f4scale(a3, 1.0f / (c3 > 0 ? (float)c3 : BIGF));
        ((float4*)(aug + 3 * H))[col] = f4scale(a4, 1.0f / (c4 > 0 ? (float)c4 : BIGF));
        ((float4*)(aug + 4 * H))[col] = f4scale(a5, 1.0f / (c5 > 0 ? (float)c5 : BIGF));
        ((float4*)paper)[col]         = f4scale(t,  1.0f / (ct > 0 ? (float)ct : BIGF));

        if (col == 0) {
            augmask[0] = c1 > 0 ? 1.0f : 0.0f;
            augmask[1] = c2 > 0 ? 1.0f : 0.0f;
            augmask[2] = c3 > 0 ? 1.0f : 0.0f;
            augmask[3] = c4 > 0 ? 1.0f : 0.0f;
            augmask[4] = c5 > 0 ? 1.0f : 0.0f;
            mask2[0]   = ct > 0 ? 1.0f : 0.0f;
        }
    }
}

extern "C" void kernel_launch(void* const* d_in, const int* in_sizes, int n_in,
                              void* d_out, int out_size, void* d_ws, size_t ws_size,
                              hipStream_t stream) {
    const float* tar_state = (const float*)d_in[0];
    const int*   tar_func  = (const int*)d_in[1];
    const float* ref_state = (const float*)d_in[2];
    const int*   ref_func  = (const int*)d_in[3];
    float* out = (float*)d_out;

    if (ws_size >= WS_NEED) {
        float* wsum = (float*)d_ws;
        int*   wcnt = (int*)((char*)d_ws + WCNT_OFF_B);
        emenc_stage1<<<NBLK1, 256, 0, stream>>>(tar_state, tar_func,
                                                ref_state, ref_func, wsum, wcnt);
        emenc_stage2<<<264 * 6, 128, 0, stream>>>(wsum, wcnt, out);
    } else {
        emenc_single<<<264, 256, 0, stream>>>(tar_state, tar_func,
                                              ref_state, ref_func, out);
    }
}